// Round 1
// baseline (72.771 us; speedup 1.0000x reference)
//
#include <hip/hip_runtime.h>
#include <hip/hip_bf16.h>
#include <math.h>

// KAN layer fused kernel for MI355X (gfx950).
// BATCH=32768, IN_FEATURES=64, GRID=64, WIDTH=64, DEGREE=3, knots clamped uniform.
//
// Layout: 512 blocks x 256 threads; each block owns 64 batch rows.
// Per feature f: coeff slab (64g x 64w) staged to LDS as bf16 (double-buffered).
// Basis weights (4 per (row,f)) computed once per (row,f) in a phase every 8 features.
// Accumulate: lane = rsub(0..7 rows) x wc(0..7 widths of 8); ds_read_b128 of 8 bf16.

#define NTHREADS 256

__device__ __forceinline__ unsigned int f2bf1(float f) {
    unsigned int u = __float_as_uint(f);
    return (u + 0x7fffu + ((u >> 16) & 1u)) >> 16;   // RNE bf16
}
__device__ __forceinline__ unsigned int packbf(float lo, float hi) {
    return f2bf1(lo) | (f2bf1(hi) << 16);
}

__global__ __launch_bounds__(NTHREADS) void kan_fused(
    const float* __restrict__ x_g,      // [32768][64]
    const float* __restrict__ shift_g,  // [64]
    const float* __restrict__ lsc_g,    // [64]
    const float* __restrict__ coeff_g,  // [64][64][64] (f,g,w)
    const float* __restrict__ skipW_g,  // [64][64] (w,f)
    const float* __restrict__ skipb_g,  // [64]
    const float* __restrict__ bias_g,   // [64]
    const float* __restrict__ gamma_g,  // [64]
    const float* __restrict__ beta_g,   // [64]
    const float* __restrict__ knots_g,  // [68]
    float* __restrict__ out_g)          // [32768][64]
{
    __shared__ float xin[64][68];              // padded: stride 68 (16B-aligned rows)
    __shared__ float4 wtab[512];               // [fc 0..7][row 0..63] -> 4 weights
    __shared__ int   g0tab[512];
    __shared__ unsigned short slab[2][4096];   // bf16 coeff slab [g][w]
    __shared__ unsigned short skw[4096];       // bf16 skip W, [f][w]
    __shared__ float knot_s[68];
    __shared__ float scale_s[64];
    __shared__ float shift_s[64];

    const int t = threadIdx.x;
    const int row0 = blockIdx.x * 64;

    // ---------------- prologue staging ----------------
    {   // inputs: 64 rows x 64 f
        const int r = t >> 2, fb = (t & 3) << 4;
        const float4* src = (const float4*)(x_g + (size_t)(row0 + r) * 64 + fb);
        float4 a0 = src[0], a1 = src[1], a2 = src[2], a3 = src[3];
        float4* dst = (float4*)(&xin[r][fb]);
        dst[0] = a0; dst[1] = a1; dst[2] = a2; dst[3] = a3;
    }
    {   // skip W: read [w][f] coalesced, write bf16 transposed [f][w]
        const float4* src = (const float4*)(skipW_g + t * 16);
        float4 a0 = src[0], a1 = src[1], a2 = src[2], a3 = src[3];
        const int w = t >> 2;
        const int f0 = (t & 3) << 4;
        float v[16];
        v[0]=a0.x; v[1]=a0.y; v[2]=a0.z; v[3]=a0.w;
        v[4]=a1.x; v[5]=a1.y; v[6]=a1.z; v[7]=a1.w;
        v[8]=a2.x; v[9]=a2.y; v[10]=a2.z; v[11]=a2.w;
        v[12]=a3.x; v[13]=a3.y; v[14]=a3.z; v[15]=a3.w;
        #pragma unroll
        for (int q = 0; q < 16; ++q)
            skw[(f0 + q) * 64 + w] = (unsigned short)f2bf1(v[q]);
    }
    if (t < 64) {
        const float l = lsc_g[t];
        scale_s[t] = log1pf(__expf(l)) + 0.001f;   // softplus + 0.001
        shift_s[t] = shift_g[t];
    }
    if (t < 68) knot_s[t] = knots_g[t];
    {   // stage slab for f=0
        const float4* src = (const float4*)(coeff_g + t * 16);
        float4 a0 = src[0], a1 = src[1], a2 = src[2], a3 = src[3];
        uint4 p0, p1;
        p0.x = packbf(a0.x, a0.y); p0.y = packbf(a0.z, a0.w);
        p0.z = packbf(a1.x, a1.y); p0.w = packbf(a1.z, a1.w);
        p1.x = packbf(a2.x, a2.y); p1.y = packbf(a2.z, a2.w);
        p1.z = packbf(a3.x, a3.y); p1.w = packbf(a3.z, a3.w);
        uint4* d = (uint4*)(&slab[0][t * 16]);
        d[0] = p0; d[1] = p1;
    }
    __syncthreads();

    const int lane = t & 63;
    const int wave = t >> 6;        // 0..3 -> rows wave*16 .. +15
    const int rsub = lane >> 3;     // 0..7
    const int wc   = lane & 7;      // 0..7
    const int w8   = wc << 3;       // widths w8..w8+7

    float acc[2][8];
    #pragma unroll
    for (int g = 0; g < 2; ++g)
        #pragma unroll
        for (int k = 0; k < 8; ++k) acc[g][k] = 0.f;

    int buf = 0;
    for (int f = 0; f < 64; ++f) {
        if ((f & 7) == 0) {
            // weights for features f..f+7, all 64 rows (512 entries, 2/thread)
            #pragma unroll
            for (int e0 = 0; e0 < 512; e0 += 256) {
                const int e = e0 + t;
                const int fc = e >> 6, r = e & 63;
                const int feat = f + fc;
                const float x0 = xin[r][feat];
                const float xs = (x0 - shift_s[feat]) * scale_s[feat];
                const float xq = 1.f / (1.f + __expf(-xs));   // in [0,1]
                int m = (int)floorf(xq * 61.f);
                m = m < 0 ? 0 : (m > 60 ? 60 : m);
                const int i = m + 3;                          // knot span
                float left[4], right[4], N[4];
                N[0] = 1.f;
                #pragma unroll
                for (int j = 1; j <= 3; ++j) {
                    left[j]  = xq - knot_s[i + 1 - j];
                    right[j] = knot_s[i + j] - xq;
                    float saved = 0.f;
                    #pragma unroll
                    for (int rr = 0; rr < j; ++rr) {
                        const float temp = N[rr] / (right[rr + 1] + left[j - rr]);
                        N[rr] = saved + right[rr + 1] * temp;
                        saved = left[j - rr] * temp;
                    }
                    N[j] = saved;
                }
                wtab[e] = make_float4(N[0], N[1], N[2], N[3]);
                g0tab[e] = m;
            }
            __syncthreads();
        }

        // prefetch next feature's slab (issue loads early; write after compute)
        float4 a0, a1, a2, a3;
        if (f < 63) {
            const float4* src = (const float4*)(coeff_g + (size_t)(f + 1) * 4096 + t * 16);
            a0 = src[0]; a1 = src[1]; a2 = src[2]; a3 = src[3];
        }

        // ------- accumulate feature f -------
        {
            const int fc = f & 7;
            const uint4 swp = *((const uint4*)(&skw[f * 64 + w8]));
            float sw[8];
            sw[0] = __uint_as_float(swp.x << 16);
            sw[1] = __uint_as_float(swp.x & 0xffff0000u);
            sw[2] = __uint_as_float(swp.y << 16);
            sw[3] = __uint_as_float(swp.y & 0xffff0000u);
            sw[4] = __uint_as_float(swp.z << 16);
            sw[5] = __uint_as_float(swp.z & 0xffff0000u);
            sw[6] = __uint_as_float(swp.w << 16);
            sw[7] = __uint_as_float(swp.w & 0xffff0000u);
            #pragma unroll
            for (int g = 0; g < 2; ++g) {
                const int row = wave * 16 + g * 8 + rsub;
                const float4 wv = wtab[fc * 64 + row];
                const int g0 = g0tab[fc * 64 + row];
                const float xv = xin[row][f];
                const unsigned short* sp = &slab[buf][g0 * 64 + w8];
                const float wjs[4] = {wv.x, wv.y, wv.z, wv.w};
                #pragma unroll
                for (int j = 0; j < 4; ++j) {
                    const uint4 cp = *((const uint4*)(sp + j * 64));
                    const float wj = wjs[j];
                    acc[g][0] += wj * __uint_as_float(cp.x << 16);
                    acc[g][1] += wj * __uint_as_float(cp.x & 0xffff0000u);
                    acc[g][2] += wj * __uint_as_float(cp.y << 16);
                    acc[g][3] += wj * __uint_as_float(cp.y & 0xffff0000u);
                    acc[g][4] += wj * __uint_as_float(cp.z << 16);
                    acc[g][5] += wj * __uint_as_float(cp.z & 0xffff0000u);
                    acc[g][6] += wj * __uint_as_float(cp.w << 16);
                    acc[g][7] += wj * __uint_as_float(cp.w & 0xffff0000u);
                }
                #pragma unroll
                for (int k = 0; k < 8; ++k) acc[g][k] += xv * sw[k];
            }
        }

        // write prefetched slab
        if (f < 63) {
            uint4 p0, p1;
            p0.x = packbf(a0.x, a0.y); p0.y = packbf(a0.z, a0.w);
            p0.z = packbf(a1.x, a1.y); p0.w = packbf(a1.z, a1.w);
            p1.x = packbf(a2.x, a2.y); p1.y = packbf(a2.z, a2.w);
            p1.z = packbf(a3.x, a3.y); p1.w = packbf(a3.z, a3.w);
            uint4* d = (uint4*)(&slab[buf ^ 1][t * 16]);
            d[0] = p0; d[1] = p1;
        }
        __syncthreads();
        buf ^= 1;
    }

    // ---------------- epilogue: bias + LN + GELU ----------------
    const float4 sb0 = *((const float4*)(skipb_g + w8));
    const float4 sb1 = *((const float4*)(skipb_g + w8 + 4));
    const float4 bi0 = *((const float4*)(bias_g + w8));
    const float4 bi1 = *((const float4*)(bias_g + w8 + 4));
    const float4 ga0 = *((const float4*)(gamma_g + w8));
    const float4 ga1 = *((const float4*)(gamma_g + w8 + 4));
    const float4 be0 = *((const float4*)(beta_g + w8));
    const float4 be1 = *((const float4*)(beta_g + w8 + 4));
    const float add_[8] = {sb0.x + bi0.x, sb0.y + bi0.y, sb0.z + bi0.z, sb0.w + bi0.w,
                           sb1.x + bi1.x, sb1.y + bi1.y, sb1.z + bi1.z, sb1.w + bi1.w};
    const float gam[8] = {ga0.x, ga0.y, ga0.z, ga0.w, ga1.x, ga1.y, ga1.z, ga1.w};
    const float bet[8] = {be0.x, be0.y, be0.z, be0.w, be1.x, be1.y, be1.z, be1.w};

    #pragma unroll
    for (int g = 0; g < 2; ++g) {
        const int row = wave * 16 + g * 8 + rsub;
        float c[8];
        #pragma unroll
        for (int k = 0; k < 8; ++k) c[k] = acc[g][k] + add_[k];
        float s = 0.f;
        #pragma unroll
        for (int k = 0; k < 8; ++k) s += c[k];
        s += __shfl_xor(s, 1); s += __shfl_xor(s, 2); s += __shfl_xor(s, 4);
        const float mean = s * 0.015625f;
        float v = 0.f;
        #pragma unroll
        for (int k = 0; k < 8; ++k) { const float d = c[k] - mean; v += d * d; }
        v += __shfl_xor(v, 1); v += __shfl_xor(v, 2); v += __shfl_xor(v, 4);
        const float inv = rsqrtf(v * 0.015625f + 1e-5f);
        float o[8];
        #pragma unroll
        for (int k = 0; k < 8; ++k) {
            const float y = (c[k] - mean) * inv * gam[k] + bet[k];
            o[k] = 0.5f * y * (1.f + erff(y * 0.70710678118f));
        }
        float4* dst = (float4*)(out_g + (size_t)(row0 + row) * 64 + w8);
        dst[0] = make_float4(o[0], o[1], o[2], o[3]);
        dst[1] = make_float4(o[4], o[5], o[6], o[7]);
    }
}

extern "C" void kernel_launch(void* const* d_in, const int* in_sizes, int n_in,
                              void* d_out, int out_size, void* d_ws, size_t ws_size,
                              hipStream_t stream) {
    (void)in_sizes; (void)n_in; (void)d_ws; (void)ws_size; (void)out_size;
    kan_fused<<<512, NTHREADS, 0, stream>>>(
        (const float*)d_in[0], (const float*)d_in[1], (const float*)d_in[2],
        (const float*)d_in[3], (const float*)d_in[4], (const float*)d_in[5],
        (const float*)d_in[6], (const float*)d_in[7], (const float*)d_in[8],
        (const float*)d_in[9], (float*)d_out);
}

// Round 2
// 68.378 us; speedup vs baseline: 1.0642x; 1.0642x over previous
//
#include <hip/hip_runtime.h>
#include <hip/hip_bf16.h>
#include <math.h>

// KAN layer fused kernel for MI355X (gfx950), round 2.
// BATCH=32768, IN_FEATURES=64, GRID=64, WIDTH=64, DEGREE=3, clamped uniform knots.
//
// 512 blocks x 512 threads; each block owns 64 rows; each thread 1 row x 8 widths.
// Coeff slab (64g x 64w) in LDS as bf16, double-buffered, XOR-swizzled by (row&7)
// at 16B granularity to kill the 8-way gather bank conflict.
// Prep kernel pre-converts coeffs to bf16 with the swizzle baked into the global
// layout (m173 pattern): hot-loop staging = 1 uint4 load + 1 uint4 store.

#define NTHREADS 512

__device__ __forceinline__ unsigned int f2bf1(float f) {
    unsigned int u = __float_as_uint(f);
    return (u + 0x7fffu + ((u >> 16) & 1u)) >> 16;   // RNE bf16
}
__device__ __forceinline__ unsigned int packbf(float lo, float hi) {
    return f2bf1(lo) | (f2bf1(hi) << 16);
}

// prep: coeff f32 [64][64][64] -> bf16 pre-swizzled LDS image [64][4096]
__global__ __launch_bounds__(512) void kan_prep(
    const float* __restrict__ coeff_g,
    unsigned short* __restrict__ ws_bf)
{
    const int f = blockIdx.x;          // 64
    const int t = threadIdx.x;         // 512
    const int g = t >> 3, s = t & 7;
    const int src_slot = s ^ (g & 7);  // inverse of read-side XOR (involution)
    const float* src = coeff_g + (size_t)f * 4096 + g * 64 + src_slot * 8;
    const float4 a0 = ((const float4*)src)[0];
    const float4 a1 = ((const float4*)src)[1];
    uint4 p;
    p.x = packbf(a0.x, a0.y); p.y = packbf(a0.z, a0.w);
    p.z = packbf(a1.x, a1.y); p.w = packbf(a1.z, a1.w);
    ((uint4*)(ws_bf + (size_t)f * 4096))[t] = p;
}

template<bool PRE>
__global__ __launch_bounds__(NTHREADS) void kan_fused(
    const float* __restrict__ x_g,      // [32768][64]
    const float* __restrict__ shift_g,  // [64]
    const float* __restrict__ lsc_g,    // [64]
    const float* __restrict__ coeff_g,  // [64][64][64] (f,g,w)
    const float* __restrict__ skipW_g,  // [64][64] (w,f)
    const float* __restrict__ skipb_g,  // [64]
    const float* __restrict__ bias_g,   // [64]
    const float* __restrict__ gamma_g,  // [64]
    const float* __restrict__ beta_g,   // [64]
    const float* __restrict__ knots_g,  // [68]
    const unsigned short* __restrict__ ws_bf,
    float* __restrict__ out_g)          // [32768][64]
{
    __shared__ float xin[64][64];              // [f][row] (transposed)
    __shared__ float4 wtab[512];               // [fc][row] -> 4 basis weights
    __shared__ int   g0tab[512];
    __shared__ unsigned short slab[2][4096];   // bf16 coeff slab, swizzled image
    __shared__ unsigned short skw[4096];       // bf16 skip W, [f][w]
    __shared__ float knot_s[68];
    __shared__ float scale_s[64];
    __shared__ float shift_s[64];

    const int t = threadIdx.x;
    const int row0 = blockIdx.x * 64;

    // ---------------- prologue staging ----------------
    {   // inputs: transpose to [f][row]
        const int r = t >> 3, f0 = (t & 7) << 3;
        const float4* src = (const float4*)(x_g + (size_t)(row0 + r) * 64 + f0);
        const float4 a0 = src[0], a1 = src[1];
        xin[f0 + 0][r] = a0.x; xin[f0 + 1][r] = a0.y;
        xin[f0 + 2][r] = a0.z; xin[f0 + 3][r] = a0.w;
        xin[f0 + 4][r] = a1.x; xin[f0 + 5][r] = a1.y;
        xin[f0 + 6][r] = a1.z; xin[f0 + 7][r] = a1.w;
    }
    {   // skip W: read [w][f] coalesced, write bf16 transposed [f][w]
        const int w = t >> 3, f0 = (t & 7) << 3;
        const float4* src = (const float4*)(skipW_g + (size_t)w * 64 + f0);
        const float4 a0 = src[0], a1 = src[1];
        skw[(f0 + 0) * 64 + w] = (unsigned short)f2bf1(a0.x);
        skw[(f0 + 1) * 64 + w] = (unsigned short)f2bf1(a0.y);
        skw[(f0 + 2) * 64 + w] = (unsigned short)f2bf1(a0.z);
        skw[(f0 + 3) * 64 + w] = (unsigned short)f2bf1(a0.w);
        skw[(f0 + 4) * 64 + w] = (unsigned short)f2bf1(a1.x);
        skw[(f0 + 5) * 64 + w] = (unsigned short)f2bf1(a1.y);
        skw[(f0 + 6) * 64 + w] = (unsigned short)f2bf1(a1.z);
        skw[(f0 + 7) * 64 + w] = (unsigned short)f2bf1(a1.w);
    }
    if (t < 64) {
        scale_s[t] = log1pf(__expf(lsc_g[t])) + 0.001f;   // softplus + 0.001
        shift_s[t] = shift_g[t];
    }
    if (t < 68) knot_s[t] = knots_g[t];
    if (PRE) {   // slab f=0 from pre-swizzled bf16
        const uint4 cp = ((const uint4*)ws_bf)[t];
        ((uint4*)slab[0])[t] = cp;
    } else {     // slab f=0 from f32 (swizzled source, linear write)
        const int g = t >> 3, s = t & 7;
        const int src_slot = s ^ (g & 7);
        const float* src = coeff_g + g * 64 + src_slot * 8;
        const float4 a0 = ((const float4*)src)[0];
        const float4 a1 = ((const float4*)src)[1];
        uint4 p;
        p.x = packbf(a0.x, a0.y); p.y = packbf(a0.z, a0.w);
        p.z = packbf(a1.x, a1.y); p.w = packbf(a1.z, a1.w);
        ((uint4*)slab[0])[t] = p;
    }
    __syncthreads();

    const int lane = t & 63;
    const int wave = t >> 6;        // 0..7
    const int rsub = lane >> 3;     // 0..7
    const int wc   = lane & 7;      // 0..7
    const int w8   = wc << 3;       // widths w8..w8+7
    const int row  = (wave << 3) + rsub;   // 0..63

    float acc[8];
    #pragma unroll
    for (int k = 0; k < 8; ++k) acc[k] = 0.f;

    int buf = 0;
    for (int f = 0; f < 64; ++f) {
        if ((f & 7) == 0) {
            // basis weights for features f..f+7, all 64 rows (512 entries, 1/thread)
            const int fc = t >> 6, r = t & 63;
            const int feat = f + fc;
            const float x0 = xin[feat][r];
            const float xs = (x0 - shift_s[feat]) * scale_s[feat];
            const float xq = 1.f / (1.f + __expf(-xs));   // sigmoid in [0,1]
            int m = (int)floorf(xq * 61.f);
            m = m < 0 ? 0 : (m > 60 ? 60 : m);
            const int i = m + 3;                          // knot span
            float left[4], right[4], N[4];
            N[0] = 1.f;
            #pragma unroll
            for (int j = 1; j <= 3; ++j) {
                left[j]  = xq - knot_s[i + 1 - j];
                right[j] = knot_s[i + j] - xq;
                float saved = 0.f;
                #pragma unroll
                for (int rr = 0; rr < j; ++rr) {
                    const float temp = N[rr] * __builtin_amdgcn_rcpf(right[rr + 1] + left[j - rr]);
                    N[rr] = saved + right[rr + 1] * temp;
                    saved = left[j - rr] * temp;
                }
                N[j] = saved;
            }
            wtab[t] = make_float4(N[0], N[1], N[2], N[3]);
            g0tab[t] = m;
            __syncthreads();
        }

        // prefetch next feature's slab (issue early, write after compute)
        uint4 cp;
        float4 a0, a1;
        if (f < 63) {
            if (PRE) {
                cp = ((const uint4*)(ws_bf + (size_t)(f + 1) * 4096))[t];
            } else {
                const int g = t >> 3, s = t & 7;
                const int src_slot = s ^ (g & 7);
                const float* src = coeff_g + (size_t)(f + 1) * 4096 + g * 64 + src_slot * 8;
                a0 = ((const float4*)src)[0];
                a1 = ((const float4*)src)[1];
            }
        }

        // ------- accumulate feature f -------
        {
            const int fc = f & 7;
            const uint4 swp = *((const uint4*)(&skw[f * 64 + w8]));
            float sw[8];
            sw[0] = __uint_as_float(swp.x << 16);
            sw[1] = __uint_as_float(swp.x & 0xffff0000u);
            sw[2] = __uint_as_float(swp.y << 16);
            sw[3] = __uint_as_float(swp.y & 0xffff0000u);
            sw[4] = __uint_as_float(swp.z << 16);
            sw[5] = __uint_as_float(swp.z & 0xffff0000u);
            sw[6] = __uint_as_float(swp.w << 16);
            sw[7] = __uint_as_float(swp.w & 0xffff0000u);
            const float4 wv = wtab[(fc << 6) + row];
            const int g0 = g0tab[(fc << 6) + row];
            const float xv = xin[f][row];
            const float wjs[4] = {wv.x, wv.y, wv.z, wv.w};
            #pragma unroll
            for (int j = 0; j < 4; ++j) {
                const int r = g0 + j;
                const uint4 cj = *((const uint4*)(&slab[buf][(r << 6) + ((wc ^ (r & 7)) << 3)]));
                const float wj = wjs[j];
                acc[0] += wj * __uint_as_float(cj.x << 16);
                acc[1] += wj * __uint_as_float(cj.x & 0xffff0000u);
                acc[2] += wj * __uint_as_float(cj.y << 16);
                acc[3] += wj * __uint_as_float(cj.y & 0xffff0000u);
                acc[4] += wj * __uint_as_float(cj.z << 16);
                acc[5] += wj * __uint_as_float(cj.z & 0xffff0000u);
                acc[6] += wj * __uint_as_float(cj.w << 16);
                acc[7] += wj * __uint_as_float(cj.w & 0xffff0000u);
            }
            #pragma unroll
            for (int k = 0; k < 8; ++k) acc[k] += xv * sw[k];
        }

        // write prefetched slab (linear — swizzle already baked into source)
        if (f < 63) {
            if (PRE) {
                ((uint4*)slab[buf ^ 1])[t] = cp;
            } else {
                uint4 p;
                p.x = packbf(a0.x, a0.y); p.y = packbf(a0.z, a0.w);
                p.z = packbf(a1.x, a1.y); p.w = packbf(a1.z, a1.w);
                ((uint4*)slab[buf ^ 1])[t] = p;
            }
        }
        __syncthreads();
        buf ^= 1;
    }

    // ---------------- epilogue: bias + LN + GELU ----------------
    const float4 sb0 = *((const float4*)(skipb_g + w8));
    const float4 sb1 = *((const float4*)(skipb_g + w8 + 4));
    const float4 bi0 = *((const float4*)(bias_g + w8));
    const float4 bi1 = *((const float4*)(bias_g + w8 + 4));
    const float4 ga0 = *((const float4*)(gamma_g + w8));
    const float4 ga1 = *((const float4*)(gamma_g + w8 + 4));
    const float4 be0 = *((const float4*)(beta_g + w8));
    const float4 be1 = *((const float4*)(beta_g + w8 + 4));
    const float add_[8] = {sb0.x + bi0.x, sb0.y + bi0.y, sb0.z + bi0.z, sb0.w + bi0.w,
                           sb1.x + bi1.x, sb1.y + bi1.y, sb1.z + bi1.z, sb1.w + bi1.w};
    const float gam[8] = {ga0.x, ga0.y, ga0.z, ga0.w, ga1.x, ga1.y, ga1.z, ga1.w};
    const float bet[8] = {be0.x, be0.y, be0.z, be0.w, be1.x, be1.y, be1.z, be1.w};

    float c[8];
    #pragma unroll
    for (int k = 0; k < 8; ++k) c[k] = acc[k] + add_[k];
    float s = 0.f;
    #pragma unroll
    for (int k = 0; k < 8; ++k) s += c[k];
    s += __shfl_xor(s, 1); s += __shfl_xor(s, 2); s += __shfl_xor(s, 4);
    const float mean = s * 0.015625f;
    float v = 0.f;
    #pragma unroll
    for (int k = 0; k < 8; ++k) { const float d = c[k] - mean; v += d * d; }
    v += __shfl_xor(v, 1); v += __shfl_xor(v, 2); v += __shfl_xor(v, 4);
    const float inv = rsqrtf(v * 0.015625f + 1e-5f);
    float o[8];
    #pragma unroll
    for (int k = 0; k < 8; ++k) {
        const float y = (c[k] - mean) * inv * gam[k] + bet[k];
        o[k] = 0.5f * y * (1.f + erff(y * 0.70710678118f));
    }
    float4* dst = (float4*)(out_g + (size_t)(row0 + row) * 64 + w8);
    dst[0] = make_float4(o[0], o[1], o[2], o[3]);
    dst[1] = make_float4(o[4], o[5], o[6], o[7]);
}

extern "C" void kernel_launch(void* const* d_in, const int* in_sizes, int n_in,
                              void* d_out, int out_size, void* d_ws, size_t ws_size,
                              hipStream_t stream) {
    (void)in_sizes; (void)n_in; (void)out_size;
    const bool pre = (ws_size >= (size_t)(64 * 64 * 64 * 2));
    if (pre) {
        kan_prep<<<64, 512, 0, stream>>>((const float*)d_in[3], (unsigned short*)d_ws);
        kan_fused<true><<<512, NTHREADS, 0, stream>>>(
            (const float*)d_in[0], (const float*)d_in[1], (const float*)d_in[2],
            (const float*)d_in[3], (const float*)d_in[4], (const float*)d_in[5],
            (const float*)d_in[6], (const float*)d_in[7], (const float*)d_in[8],
            (const float*)d_in[9], (const unsigned short*)d_ws, (float*)d_out);
    } else {
        kan_fused<false><<<512, NTHREADS, 0, stream>>>(
            (const float*)d_in[0], (const float*)d_in[1], (const float*)d_in[2],
            (const float*)d_in[3], (const float*)d_in[4], (const float*)d_in[5],
            (const float*)d_in[6], (const float*)d_in[7], (const float*)d_in[8],
            (const float*)d_in[9], (const unsigned short*)d_ws, (float*)d_out);
    }
}

// Round 3
// 66.057 us; speedup vs baseline: 1.1016x; 1.0351x over previous
//
#include <hip/hip_runtime.h>
#include <math.h>

// KAN layer fused kernel for MI355X (gfx950), round 3.
// BATCH=32768, IN_FEATURES=64, GRID=64, WIDTH=64, DEGREE=3, clamped uniform knots.
//
// 1024 blocks x 256 threads; 32 rows/block; thread = (row, 8 widths).
// Skip-GEMM hoisted to a prologue pass that reuses the coeff slab buffer for W.
// Coeff slab single-buffered (8 KB) with reg-staged prefetch (T14 split).
// LDS ~22 KB -> 7 blocks/CU (~28 waves/CU). Packed f32 math (v_pk_fma_f32) via
// ext_vector float2. No LDS swizzle (measured neutral: conflict is cross-row,
// inherent to the 8-row gather shape).

#define NTHREADS 256
#define ROWS 32

typedef float v2f __attribute__((ext_vector_type(2)));

__device__ __forceinline__ unsigned int f2bf1(float f) {
    unsigned int u = __float_as_uint(f);
    return (u + 0x7fffu + ((u >> 16) & 1u)) >> 16;   // RNE bf16
}
__device__ __forceinline__ unsigned int packbf(float lo, float hi) {
    return f2bf1(lo) | (f2bf1(hi) << 16);
}
__device__ __forceinline__ v2f up2(unsigned int u) {   // uint(2x bf16) -> 2x f32
    v2f r;
    r.x = __uint_as_float(u << 16);
    r.y = __uint_as_float(u & 0xffff0000u);
    return r;
}

// prep: coeff f32 [64][64][64] -> bf16 image [64][4096] (linear)
__global__ __launch_bounds__(512) void kan_prep(
    const float* __restrict__ coeff_g,
    unsigned short* __restrict__ ws_bf)
{
    const int f = blockIdx.x;          // 64
    const int t = threadIdx.x;         // 512
    const float* src = coeff_g + (size_t)f * 4096 + t * 8;
    const float4 a0 = ((const float4*)src)[0];
    const float4 a1 = ((const float4*)src)[1];
    uint4 p;
    p.x = packbf(a0.x, a0.y); p.y = packbf(a0.z, a0.w);
    p.z = packbf(a1.x, a1.y); p.w = packbf(a1.z, a1.w);
    ((uint4*)(ws_bf + (size_t)f * 4096))[t] = p;
}

template<bool PRE>
__global__ __launch_bounds__(NTHREADS, 7) void kan_fused(
    const float* __restrict__ x_g,      // [32768][64]
    const float* __restrict__ shift_g,  // [64]
    const float* __restrict__ lsc_g,    // [64]
    const float* __restrict__ coeff_g,  // [64][64][64] (f,g,w)
    const float* __restrict__ skipW_g,  // [64][64] (w,f)
    const float* __restrict__ skipb_g,  // [64]
    const float* __restrict__ bias_g,   // [64]
    const float* __restrict__ gamma_g,  // [64]
    const float* __restrict__ beta_g,   // [64]
    const float* __restrict__ knots_g,  // [68]
    const unsigned short* __restrict__ ws_bf,
    float* __restrict__ out_g)          // [32768][64]
{
    __shared__ float  xin[64][ROWS];        // 8 KB  [f][row]
    __shared__ float4 wtab[8 * ROWS];       // 4 KB  [fc][row]
    __shared__ int    g0tab[8 * ROWS];      // 1 KB
    __shared__ uint4  slab4[512];           // 8 KB  (skip-W bf16, then coeff slab)
    __shared__ float  knot_s[68];
    __shared__ float  scale_s[64];
    __shared__ float  shift_s[64];
    unsigned short* const slab = (unsigned short*)slab4;

    const int t = threadIdx.x;
    const int row0 = blockIdx.x * ROWS;

    // ---------------- prologue staging ----------------
    {   // inputs: transpose to [f][row]
        const int r = t >> 3, f0 = (t & 7) << 3;
        const float4* src = (const float4*)(x_g + (size_t)(row0 + r) * 64 + f0);
        const float4 a0 = src[0], a1 = src[1];
        xin[f0 + 0][r] = a0.x; xin[f0 + 1][r] = a0.y;
        xin[f0 + 2][r] = a0.z; xin[f0 + 3][r] = a0.w;
        xin[f0 + 4][r] = a1.x; xin[f0 + 5][r] = a1.y;
        xin[f0 + 6][r] = a1.z; xin[f0 + 7][r] = a1.w;
    }
    {   // skip W: read [w][f] coalesced, write bf16 transposed [f][w] into slab
        const int w = t >> 2, f0 = (t & 3) << 4;
        const float4* src = (const float4*)(skipW_g + (size_t)w * 64 + f0);
        const float4 a0 = src[0], a1 = src[1], a2 = src[2], a3 = src[3];
        float v[16];
        v[0]=a0.x; v[1]=a0.y; v[2]=a0.z; v[3]=a0.w;
        v[4]=a1.x; v[5]=a1.y; v[6]=a1.z; v[7]=a1.w;
        v[8]=a2.x; v[9]=a2.y; v[10]=a2.z; v[11]=a2.w;
        v[12]=a3.x; v[13]=a3.y; v[14]=a3.z; v[15]=a3.w;
        #pragma unroll
        for (int q = 0; q < 16; ++q)
            slab[(f0 + q) * 64 + w] = (unsigned short)f2bf1(v[q]);
    }
    if (t < 64) {
        scale_s[t] = log1pf(__expf(lsc_g[t])) + 0.001f;   // softplus + 0.001
        shift_s[t] = shift_g[t];
    }
    if (t < 68) knot_s[t] = knots_g[t];
    __syncthreads();

    const int lane = t & 63;
    const int wave = t >> 6;        // 0..3
    const int rsub = lane >> 3;     // 0..7
    const int wc   = lane & 7;      // 0..7
    const int w8   = wc << 3;       // widths w8..w8+7
    const int row  = (wave << 3) + rsub;   // 0..31

    // issue coeff slab f=0 loads early (T14: write after the skip pass)
    uint4 cp0, cp1;
    if (PRE) {
        cp0 = ((const uint4*)ws_bf)[t];
        cp1 = ((const uint4*)ws_bf)[t + 256];
    } else {
        const float4* s0 = (const float4*)(coeff_g + t * 8);
        const float4* s1 = (const float4*)(coeff_g + 2048 + t * 8);
        const float4 a0 = s0[0], a1 = s0[1], b0 = s1[0], b1 = s1[1];
        cp0.x = packbf(a0.x, a0.y); cp0.y = packbf(a0.z, a0.w);
        cp0.z = packbf(a1.x, a1.y); cp0.w = packbf(a1.z, a1.w);
        cp1.x = packbf(b0.x, b0.y); cp1.y = packbf(b0.z, b0.w);
        cp1.z = packbf(b1.x, b1.y); cp1.w = packbf(b1.z, b1.w);
    }

    // ---------------- skip pass: acc += x[row][f] * W[w][f] ----------------
    v2f acc2[4];
    #pragma unroll
    for (int q = 0; q < 4; ++q) acc2[q] = (v2f){0.f, 0.f};
    #pragma unroll 4
    for (int f = 0; f < 64; ++f) {
        const float xv = xin[f][row];
        const uint4 sp = *((const uint4*)(&slab[f * 64 + w8]));
        const v2f xv2 = {xv, xv};
        acc2[0] += xv2 * up2(sp.x);
        acc2[1] += xv2 * up2(sp.y);
        acc2[2] += xv2 * up2(sp.z);
        acc2[3] += xv2 * up2(sp.w);
    }
    __syncthreads();   // skip reads of slab done

    // write coeff slab f=0
    ((uint4*)slab4)[t] = cp0;
    ((uint4*)slab4)[t + 256] = cp1;

    // basis phase group 0 (features 0..7), one (fc,row) entry per thread
    {
        const int fc_ = t >> 5, r_ = t & 31;
        const float xs = (xin[fc_][r_] - shift_s[fc_]) * scale_s[fc_];
        const float xq = 1.f / (1.f + __expf(-xs));
        int m = (int)floorf(xq * 61.f);
        m = m < 0 ? 0 : (m > 60 ? 60 : m);
        const int i = m + 3;
        float left[4], right[4], N[4];
        N[0] = 1.f;
        #pragma unroll
        for (int j = 1; j <= 3; ++j) {
            left[j]  = xq - knot_s[i + 1 - j];
            right[j] = knot_s[i + j] - xq;
            float saved = 0.f;
            #pragma unroll
            for (int rr = 0; rr < j; ++rr) {
                const float temp = N[rr] * __builtin_amdgcn_rcpf(right[rr + 1] + left[j - rr]);
                N[rr] = saved + right[rr + 1] * temp;
                saved = left[j - rr] * temp;
            }
            N[j] = saved;
        }
        wtab[t] = make_float4(N[0], N[1], N[2], N[3]);
        g0tab[t] = m;
    }
    __syncthreads();

    // ---------------- main loop over features ----------------
    for (int f = 0; f < 64; ++f) {
        // issue next slab load (consumed after barrier A)
        if (f < 63) {
            if (PRE) {
                const uint4* src = (const uint4*)(ws_bf + (size_t)(f + 1) * 4096);
                cp0 = src[t]; cp1 = src[t + 256];
            } else {
                const float* base = coeff_g + (size_t)(f + 1) * 4096;
                const float4* s0 = (const float4*)(base + t * 8);
                const float4* s1 = (const float4*)(base + 2048 + t * 8);
                const float4 a0 = s0[0], a1 = s0[1], b0 = s1[0], b1 = s1[1];
                cp0.x = packbf(a0.x, a0.y); cp0.y = packbf(a0.z, a0.w);
                cp0.z = packbf(a1.x, a1.y); cp0.w = packbf(a1.z, a1.w);
                cp1.x = packbf(b0.x, b0.y); cp1.y = packbf(b0.z, b0.w);
                cp1.z = packbf(b1.x, b1.y); cp1.w = packbf(b1.z, b1.w);
            }
        }

        // ------- accumulate feature f -------
        {
            const int fc = f & 7;
            const float4 wv = wtab[(fc << 5) + row];
            const int g0 = g0tab[(fc << 5) + row];
            const unsigned short* sp = &slab[(g0 << 6) + w8];
            const float wjs[4] = {wv.x, wv.y, wv.z, wv.w};
            #pragma unroll
            for (int j = 0; j < 4; ++j) {
                const uint4 cj = *((const uint4*)(sp + (j << 6)));
                const v2f wj2 = {wjs[j], wjs[j]};
                acc2[0] += wj2 * up2(cj.x);
                acc2[1] += wj2 * up2(cj.y);
                acc2[2] += wj2 * up2(cj.z);
                acc2[3] += wj2 * up2(cj.w);
            }
        }

        __syncthreads();   // A: all reads of slab f done

        if (f < 63) {
            ((uint4*)slab4)[t] = cp0;
            ((uint4*)slab4)[t + 256] = cp1;
        }
        if ((f & 7) == 7 && f < 63) {
            // basis phase for next feature group (wtab reads for f are done)
            const int fc_ = t >> 5, r_ = t & 31;
            const int feat = (f + 1) + fc_;
            const float xs = (xin[feat][r_] - shift_s[feat]) * scale_s[feat];
            const float xq = 1.f / (1.f + __expf(-xs));
            int m = (int)floorf(xq * 61.f);
            m = m < 0 ? 0 : (m > 60 ? 60 : m);
            const int i = m + 3;
            float left[4], right[4], N[4];
            N[0] = 1.f;
            #pragma unroll
            for (int j = 1; j <= 3; ++j) {
                left[j]  = xq - knot_s[i + 1 - j];
                right[j] = knot_s[i + j] - xq;
                float saved = 0.f;
                #pragma unroll
                for (int rr = 0; rr < j; ++rr) {
                    const float temp = N[rr] * __builtin_amdgcn_rcpf(right[rr + 1] + left[j - rr]);
                    N[rr] = saved + right[rr + 1] * temp;
                    saved = left[j - rr] * temp;
                }
                N[j] = saved;
            }
            wtab[t] = make_float4(N[0], N[1], N[2], N[3]);
            g0tab[t] = m;
        }
        __syncthreads();   // B: slab f+1 (and wtab) visible
    }

    // ---------------- epilogue: bias + LN + GELU ----------------
    const float4 sb0 = *((const float4*)(skipb_g + w8));
    const float4 sb1 = *((const float4*)(skipb_g + w8 + 4));
    const float4 bi0 = *((const float4*)(bias_g + w8));
    const float4 bi1 = *((const float4*)(bias_g + w8 + 4));
    const float4 ga0 = *((const float4*)(gamma_g + w8));
    const float4 ga1 = *((const float4*)(gamma_g + w8 + 4));
    const float4 be0 = *((const float4*)(beta_g + w8));
    const float4 be1 = *((const float4*)(beta_g + w8 + 4));
    const float add_[8] = {sb0.x + bi0.x, sb0.y + bi0.y, sb0.z + bi0.z, sb0.w + bi0.w,
                           sb1.x + bi1.x, sb1.y + bi1.y, sb1.z + bi1.z, sb1.w + bi1.w};
    const float gam[8] = {ga0.x, ga0.y, ga0.z, ga0.w, ga1.x, ga1.y, ga1.z, ga1.w};
    const float bet[8] = {be0.x, be0.y, be0.z, be0.w, be1.x, be1.y, be1.z, be1.w};

    float c[8];
    #pragma unroll
    for (int q = 0; q < 4; ++q) { c[2*q] = acc2[q].x + add_[2*q]; c[2*q+1] = acc2[q].y + add_[2*q+1]; }
    float s = 0.f;
    #pragma unroll
    for (int k = 0; k < 8; ++k) s += c[k];
    s += __shfl_xor(s, 1); s += __shfl_xor(s, 2); s += __shfl_xor(s, 4);
    const float mean = s * 0.015625f;
    float v = 0.f;
    #pragma unroll
    for (int k = 0; k < 8; ++k) { const float d = c[k] - mean; v += d * d; }
    v += __shfl_xor(v, 1); v += __shfl_xor(v, 2); v += __shfl_xor(v, 4);
    const float inv = rsqrtf(v * 0.015625f + 1e-5f);
    float o[8];
    #pragma unroll
    for (int k = 0; k < 8; ++k) {
        const float y = (c[k] - mean) * inv * gam[k] + bet[k];
        o[k] = 0.5f * y * (1.f + erff(y * 0.70710678118f));
    }
    float4* dst = (float4*)(out_g + (size_t)(row0 + row) * 64 + w8);
    dst[0] = make_float4(o[0], o[1], o[2], o[3]);
    dst[1] = make_float4(o[4], o[5], o[6], o[7]);
}

extern "C" void kernel_launch(void* const* d_in, const int* in_sizes, int n_in,
                              void* d_out, int out_size, void* d_ws, size_t ws_size,
                              hipStream_t stream) {
    (void)in_sizes; (void)n_in; (void)out_size;
    const bool pre = (ws_size >= (size_t)(64 * 64 * 64 * 2));
    if (pre) {
        kan_prep<<<64, 512, 0, stream>>>((const float*)d_in[3], (unsigned short*)d_ws);
        kan_fused<true><<<1024, NTHREADS, 0, stream>>>(
            (const float*)d_in[0], (const float*)d_in[1], (const float*)d_in[2],
            (const float*)d_in[3], (const float*)d_in[4], (const float*)d_in[5],
            (const float*)d_in[6], (const float*)d_in[7], (const float*)d_in[8],
            (const float*)d_in[9], (const unsigned short*)d_ws, (float*)d_out);
    } else {
        kan_fused<false><<<1024, NTHREADS, 0, stream>>>(
            (const float*)d_in[0], (const float*)d_in[1], (const float*)d_in[2],
            (const float*)d_in[3], (const float*)d_in[4], (const float*)d_in[5],
            (const float*)d_in[6], (const float*)d_in[7], (const float*)d_in[8],
            (const float*)d_in[9], (const unsigned short*)d_ws, (float*)d_out);
    }
}

// Round 4
// 54.436 us; speedup vs baseline: 1.3368x; 1.2135x over previous
//
#include <hip/hip_runtime.h>
#include <math.h>

// KAN layer fused kernel for MI355X (gfx950), round 4.
// BATCH=32768, IN_FEATURES=64, GRID=64, WIDTH=64, DEGREE=3, clamped uniform knots.
//
// 512 blocks x 512 threads; 64 rows/block; thread = (row, 8 widths).
// Coeff slab in fp8 e4m3, pre-scaled x16 (x1/16 folded into basis weights),
// double-buffered (4KB x2) -> ONE barrier per feature. g0 embedded in the low
// 6 mantissa bits of wtab N0/16 (saves the g0tab read). Skip-GEMM in a bf16
// prologue pass. LDS ~42KB, 2 blocks/CU, 16 waves/CU.

#define NTHREADS 512
#define ROWS 64

typedef float v2f __attribute__((ext_vector_type(2)));

__device__ __forceinline__ unsigned int f2bf1(float f) {
    unsigned int u = __float_as_uint(f);
    return (u + 0x7fffu + ((u >> 16) & 1u)) >> 16;   // RNE bf16
}
__device__ __forceinline__ v2f up2(unsigned int u) {   // 2x bf16 -> 2x f32
    v2f r;
    r.x = __uint_as_float(u << 16);
    r.y = __uint_as_float(u & 0xffff0000u);
    return r;
}
__device__ __forceinline__ unsigned int pk4fp8(float a, float b, float c, float d) {
    int u = __builtin_amdgcn_cvt_pk_fp8_f32(a, b, 0, false);
    u = __builtin_amdgcn_cvt_pk_fp8_f32(c, d, u, true);
    return (unsigned int)u;
}

// prep: coeff f32 [64][64][64] -> fp8 e4m3 (x16) image [64][4096]
__global__ __launch_bounds__(256) void kan_prep(
    const float* __restrict__ coeff_g,
    unsigned char* __restrict__ ws8)
{
    const int f = blockIdx.x;          // 64
    const int t = threadIdx.x;         // 256, 16 coeffs each
    const float* src = coeff_g + (size_t)f * 4096 + t * 16;
    const float4 a0 = ((const float4*)src)[0];
    const float4 a1 = ((const float4*)src)[1];
    const float4 a2 = ((const float4*)src)[2];
    const float4 a3 = ((const float4*)src)[3];
    uint4 p;
    p.x = pk4fp8(16.f*a0.x, 16.f*a0.y, 16.f*a0.z, 16.f*a0.w);
    p.y = pk4fp8(16.f*a1.x, 16.f*a1.y, 16.f*a1.z, 16.f*a1.w);
    p.z = pk4fp8(16.f*a2.x, 16.f*a2.y, 16.f*a2.z, 16.f*a2.w);
    p.w = pk4fp8(16.f*a3.x, 16.f*a3.y, 16.f*a3.z, 16.f*a3.w);
    ((uint4*)(ws8 + (size_t)f * 4096))[t] = p;
}

template<bool PRE>
__global__ __launch_bounds__(NTHREADS, 4) void kan_fused(
    const float* __restrict__ x_g,      // [32768][64]
    const float* __restrict__ shift_g,  // [64]
    const float* __restrict__ lsc_g,    // [64]
    const float* __restrict__ coeff_g,  // [64][64][64] (f,g,w)
    const float* __restrict__ skipW_g,  // [64][64] (w,f)
    const float* __restrict__ skipb_g,  // [64]
    const float* __restrict__ bias_g,   // [64]
    const float* __restrict__ gamma_g,  // [64]
    const float* __restrict__ beta_g,   // [64]
    const float* __restrict__ knots_g,  // [68]
    const unsigned char* __restrict__ ws8,
    float* __restrict__ out_g)          // [32768][64]
{
    __shared__ float  xin[64][ROWS];            // 16 KB [f][row]
    __shared__ unsigned short skw[4096];        // 8 KB  bf16 [f][w]
    __shared__ float4 wtab[8 * ROWS];           // 8 KB  [fc][row]: {N0/16|g0, N1/16, N2/16, N3/16}
    __shared__ unsigned char slab[2][4096];     // 8 KB  fp8 coeff slab, dbuf
    __shared__ float  knot_s[68];
    __shared__ float  scale_s[64];
    __shared__ float  shift_s[64];

    const int t = threadIdx.x;
    const int row0 = blockIdx.x * ROWS;

    // basis weights for 8 features x 64 rows; one (fc,row) per thread.
    auto basis_phase = [&](int fbase) {
        const int fc_ = t >> 6, r_ = t & 63;
        const int feat = fbase + fc_;
        const float xs = (xin[feat][r_] - shift_s[feat]) * scale_s[feat];
        const float xq = 1.f / (1.f + __expf(-xs));   // sigmoid in [0,1]
        int m = (int)floorf(xq * 61.f);
        m = m < 0 ? 0 : (m > 60 ? 60 : m);
        const int i = m + 3;
        float left[4], right[4], N[4];
        N[0] = 1.f;
        #pragma unroll
        for (int j = 1; j <= 3; ++j) {
            left[j]  = xq - knot_s[i + 1 - j];
            right[j] = knot_s[i + j] - xq;
            float saved = 0.f;
            #pragma unroll
            for (int rr = 0; rr < j; ++rr) {
                const float temp = N[rr] * __builtin_amdgcn_rcpf(right[rr + 1] + left[j - rr]);
                N[rr] = saved + right[rr + 1] * temp;
                saved = left[j - rr] * temp;
            }
            N[j] = saved;
        }
        // scale by 1/16 (fp8 slab is x16); embed g0 in low 6 mantissa bits of N0
        const float n0 = N[0] * 0.0625f;
        const unsigned int u0 = (__float_as_uint(n0) & ~63u) | (unsigned int)m;
        wtab[t] = make_float4(__uint_as_float(u0), N[1] * 0.0625f,
                              N[2] * 0.0625f, N[3] * 0.0625f);
    };

    // ---------------- prologue staging ----------------
    {   // inputs: transpose to [f][row]
        const int r = t >> 3, f0 = (t & 7) << 3;
        const float4* src = (const float4*)(x_g + (size_t)(row0 + r) * 64 + f0);
        const float4 a0 = src[0], a1 = src[1];
        xin[f0 + 0][r] = a0.x; xin[f0 + 1][r] = a0.y;
        xin[f0 + 2][r] = a0.z; xin[f0 + 3][r] = a0.w;
        xin[f0 + 4][r] = a1.x; xin[f0 + 5][r] = a1.y;
        xin[f0 + 6][r] = a1.z; xin[f0 + 7][r] = a1.w;
    }
    {   // skip W: read [w][f] coalesced, write bf16 transposed [f][w]
        const int w = t >> 3, f0 = (t & 7) << 3;
        const float4* src = (const float4*)(skipW_g + (size_t)w * 64 + f0);
        const float4 a0 = src[0], a1 = src[1];
        skw[(f0 + 0) * 64 + w] = (unsigned short)f2bf1(a0.x);
        skw[(f0 + 1) * 64 + w] = (unsigned short)f2bf1(a0.y);
        skw[(f0 + 2) * 64 + w] = (unsigned short)f2bf1(a0.z);
        skw[(f0 + 3) * 64 + w] = (unsigned short)f2bf1(a0.w);
        skw[(f0 + 4) * 64 + w] = (unsigned short)f2bf1(a1.x);
        skw[(f0 + 5) * 64 + w] = (unsigned short)f2bf1(a1.y);
        skw[(f0 + 6) * 64 + w] = (unsigned short)f2bf1(a1.z);
        skw[(f0 + 7) * 64 + w] = (unsigned short)f2bf1(a1.w);
    }
    if (t < 64) {
        scale_s[t] = log1pf(__expf(lsc_g[t])) + 0.001f;   // softplus + 0.001
        shift_s[t] = shift_g[t];
    }
    if (t < 68) knot_s[t] = knots_g[t];
    {   // slab f=0 (fp8, 8B/thread)
        uint2 c0;
        if (PRE) {
            c0 = ((const uint2*)ws8)[t];
        } else {
            const float* src = coeff_g + t * 8;
            const float4 a0 = ((const float4*)src)[0];
            const float4 a1 = ((const float4*)src)[1];
            c0.x = pk4fp8(16.f*a0.x, 16.f*a0.y, 16.f*a0.z, 16.f*a0.w);
            c0.y = pk4fp8(16.f*a1.x, 16.f*a1.y, 16.f*a1.z, 16.f*a1.w);
        }
        *((uint2*)&slab[0][t << 3]) = c0;
    }
    __syncthreads();

    const int lane = t & 63;
    const int wave = t >> 6;        // 0..7
    const int rsub = lane >> 3;     // 0..7
    const int wc   = lane & 7;      // 0..7
    const int w8   = wc << 3;       // widths w8..w8+7
    const int row  = (wave << 3) + rsub;   // 0..63

    // ---------------- skip pass: acc += x[row][f] * W[w][f] ----------------
    v2f acc2[4];
    #pragma unroll
    for (int q = 0; q < 4; ++q) acc2[q] = (v2f){0.f, 0.f};
    #pragma unroll 4
    for (int f = 0; f < 64; ++f) {
        const float xv = xin[f][row];
        const uint4 sp = *((const uint4*)(&skw[f * 64 + w8]));
        const v2f xv2 = {xv, xv};
        acc2[0] += xv2 * up2(sp.x);
        acc2[1] += xv2 * up2(sp.y);
        acc2[2] += xv2 * up2(sp.z);
        acc2[3] += xv2 * up2(sp.w);
    }
    basis_phase(0);
    __syncthreads();   // wtab group 0 + slab f0 visible

    // ---------------- main loop over features ----------------
    int buf = 0;
    for (int f = 0; f < 64; ++f) {
        // issue next slab load (written to buf^1 after compute; no read barrier
        // needed thanks to double-buffering)
        uint2 cp;
        if (f < 63) {
            if (PRE) {
                cp = ((const uint2*)(ws8 + (size_t)(f + 1) * 4096))[t];
            } else {
                const float* src = coeff_g + (size_t)(f + 1) * 4096 + t * 8;
                const float4 a0 = ((const float4*)src)[0];
                const float4 a1 = ((const float4*)src)[1];
                cp.x = pk4fp8(16.f*a0.x, 16.f*a0.y, 16.f*a0.z, 16.f*a0.w);
                cp.y = pk4fp8(16.f*a1.x, 16.f*a1.y, 16.f*a1.z, 16.f*a1.w);
            }
        }

        // ------- accumulate feature f -------
        {
            const int fc = f & 7;
            const float4 wv = wtab[(fc << 6) + row];
            const unsigned int g0 = __float_as_uint(wv.x) & 63u;
            const unsigned char* sp = &slab[buf][(g0 << 6) + w8];
            const float wjs[4] = {wv.x, wv.y, wv.z, wv.w};
            #pragma unroll
            for (int j = 0; j < 4; ++j) {
                const uint2 cj = *((const uint2*)(sp + (j << 6)));
                const v2f wj2 = {wjs[j], wjs[j]};
                v2f p;
                p = __builtin_amdgcn_cvt_pk_f32_fp8((int)cj.x, false); acc2[0] += wj2 * p;
                p = __builtin_amdgcn_cvt_pk_f32_fp8((int)cj.x, true);  acc2[1] += wj2 * p;
                p = __builtin_amdgcn_cvt_pk_f32_fp8((int)cj.y, false); acc2[2] += wj2 * p;
                p = __builtin_amdgcn_cvt_pk_f32_fp8((int)cj.y, true);  acc2[3] += wj2 * p;
            }
        }

        if ((f & 7) == 7 && f < 63) {
            __syncthreads();          // all reads of current wtab group done
            basis_phase(f + 1);       // overwrite wtab with next group
        }
        if (f < 63) *((uint2*)&slab[buf ^ 1][t << 3]) = cp;
        __syncthreads();              // slab[buf^1] (+ wtab) visible
        buf ^= 1;
    }

    // ---------------- epilogue: bias + LN + GELU ----------------
    const float4 sb0 = *((const float4*)(skipb_g + w8));
    const float4 sb1 = *((const float4*)(skipb_g + w8 + 4));
    const float4 bi0 = *((const float4*)(bias_g + w8));
    const float4 bi1 = *((const float4*)(bias_g + w8 + 4));
    const float4 ga0 = *((const float4*)(gamma_g + w8));
    const float4 ga1 = *((const float4*)(gamma_g + w8 + 4));
    const float4 be0 = *((const float4*)(beta_g + w8));
    const float4 be1 = *((const float4*)(beta_g + w8 + 4));
    const float add_[8] = {sb0.x + bi0.x, sb0.y + bi0.y, sb0.z + bi0.z, sb0.w + bi0.w,
                           sb1.x + bi1.x, sb1.y + bi1.y, sb1.z + bi1.z, sb1.w + bi1.w};
    const float gam[8] = {ga0.x, ga0.y, ga0.z, ga0.w, ga1.x, ga1.y, ga1.z, ga1.w};
    const float bet[8] = {be0.x, be0.y, be0.z, be0.w, be1.x, be1.y, be1.z, be1.w};

    float c[8];
    #pragma unroll
    for (int q = 0; q < 4; ++q) { c[2*q] = acc2[q].x + add_[2*q]; c[2*q+1] = acc2[q].y + add_[2*q+1]; }
    float s = 0.f;
    #pragma unroll
    for (int k = 0; k < 8; ++k) s += c[k];
    s += __shfl_xor(s, 1); s += __shfl_xor(s, 2); s += __shfl_xor(s, 4);
    const float mean = s * 0.015625f;
    float v = 0.f;
    #pragma unroll
    for (int k = 0; k < 8; ++k) { const float d = c[k] - mean; v += d * d; }
    v += __shfl_xor(v, 1); v += __shfl_xor(v, 2); v += __shfl_xor(v, 4);
    const float inv = rsqrtf(v * 0.015625f + 1e-5f);
    float o[8];
    #pragma unroll
    for (int k = 0; k < 8; ++k) {
        const float y = (c[k] - mean) * inv * gam[k] + bet[k];
        o[k] = 0.5f * y * (1.f + erff(y * 0.70710678118f));
    }
    float4* dst = (float4*)(out_g + (size_t)(row0 + row) * 64 + w8);
    dst[0] = make_float4(o[0], o[1], o[2], o[3]);
    dst[1] = make_float4(o[4], o[5], o[6], o[7]);
}

extern "C" void kernel_launch(void* const* d_in, const int* in_sizes, int n_in,
                              void* d_out, int out_size, void* d_ws, size_t ws_size,
                              hipStream_t stream) {
    (void)in_sizes; (void)n_in; (void)out_size;
    const bool pre = (ws_size >= (size_t)(64 * 64 * 64));
    if (pre) {
        kan_prep<<<64, 256, 0, stream>>>((const float*)d_in[3], (unsigned char*)d_ws);
        kan_fused<true><<<512, NTHREADS, 0, stream>>>(
            (const float*)d_in[0], (const float*)d_in[1], (const float*)d_in[2],
            (const float*)d_in[3], (const float*)d_in[4], (const float*)d_in[5],
            (const float*)d_in[6], (const float*)d_in[7], (const float*)d_in[8],
            (const float*)d_in[9], (const unsigned char*)d_ws, (float*)d_out);
    } else {
        kan_fused<false><<<512, NTHREADS, 0, stream>>>(
            (const float*)d_in[0], (const float*)d_in[1], (const float*)d_in[2],
            (const float*)d_in[3], (const float*)d_in[4], (const float*)d_in[5],
            (const float*)d_in[6], (const float*)d_in[7], (const float*)d_in[8],
            (const float*)d_in[9], (const unsigned char*)d_ws, (float*)d_out);
    }
}